// Round 1
// baseline (75.396 us; speedup 1.0000x reference)
//
#include <hip/hip_runtime.h>
#include <math.h>

// Per-camera precompute: compose base*rel pose, fold intrinsics.
// Output per camera: 12 floats = [M00..M22 (K@R_final row-major), v0 v1 v2 (K@t_final)]

__device__ __forceinline__ void quat_to_R(float q0, float q1, float q2, float q3, float R[9]) {
    float inv = 1.0f / sqrtf(q0 * q0 + q1 * q1 + q2 * q2 + q3 * q3);
    float x = q0 * inv, y = q1 * inv, z = q2 * inv, w = q3 * inv;
    R[0] = 1.0f - 2.0f * (y * y + z * z);
    R[1] = 2.0f * (x * y - w * z);
    R[2] = 2.0f * (x * z + w * y);
    R[3] = 2.0f * (x * y + w * z);
    R[4] = 1.0f - 2.0f * (x * x + z * z);
    R[5] = 2.0f * (y * z - w * x);
    R[6] = 2.0f * (x * z - w * y);
    R[7] = 2.0f * (y * z + w * x);
    R[8] = 1.0f - 2.0f * (x * x + y * y);
}

__global__ void cam_precompute(const float* __restrict__ base_poses,
                               const float* __restrict__ rel_poses,
                               const float* __restrict__ intr,
                               const int* __restrict__ lookup,
                               float* __restrict__ cam_mat,
                               int C) {
    int c = blockIdx.x * blockDim.x + threadIdx.x;
    if (c >= C) return;
    int bpi = lookup[2 * c + 0];
    int rpi = lookup[2 * c + 1];
    bool has_rel = (rpi != -1);
    int rs = has_rel ? rpi : 0;

    const float* bp = base_poses + 7 * bpi;
    float tb0 = bp[0], tb1 = bp[1], tb2 = bp[2];
    float Rb[9];
    quat_to_R(bp[3], bp[4], bp[5], bp[6], Rb);

    const float* rp = rel_poses + 7 * rs;
    float Rr[9];
    quat_to_R(rp[3], rp[4], rp[5], rp[6], Rr);

    float Rf[9], tf0, tf1, tf2;
    if (has_rel) {
        #pragma unroll
        for (int i = 0; i < 3; ++i) {
            #pragma unroll
            for (int j = 0; j < 3; ++j) {
                Rf[3 * i + j] = Rb[3 * i + 0] * Rr[0 + j]
                              + Rb[3 * i + 1] * Rr[3 + j]
                              + Rb[3 * i + 2] * Rr[6 + j];
            }
        }
        tf0 = tb0 + Rb[0] * rp[0] + Rb[1] * rp[1] + Rb[2] * rp[2];
        tf1 = tb1 + Rb[3] * rp[0] + Rb[4] * rp[1] + Rb[5] * rp[2];
        tf2 = tb2 + Rb[6] * rp[0] + Rb[7] * rp[1] + Rb[8] * rp[2];
    } else {
        #pragma unroll
        for (int i = 0; i < 9; ++i) Rf[i] = Rb[i];
        tf0 = tb0; tf1 = tb1; tf2 = tb2;
    }

    const float* K = intr + 9 * c;
    float M[9], v[3];
    #pragma unroll
    for (int i = 0; i < 3; ++i) {
        #pragma unroll
        for (int j = 0; j < 3; ++j) {
            M[3 * i + j] = K[3 * i + 0] * Rf[0 + j]
                         + K[3 * i + 1] * Rf[3 + j]
                         + K[3 * i + 2] * Rf[6 + j];
        }
        v[i] = K[3 * i + 0] * tf0 + K[3 * i + 1] * tf1 + K[3 * i + 2] * tf2;
    }

    float* o = cam_mat + 12 * c;
    #pragma unroll
    for (int i = 0; i < 9; ++i) o[i] = M[i];
    o[9] = v[0];
    o[10] = v[1];
    o[11] = v[2];
}

// Main per-observation kernel.
// cam_mat layout per camera (3 x float4):
//   m0 = {M00, M01, M02, M10}
//   m1 = {M11, M12, M20, M21}
//   m2 = {M22, v0,  v1,  v2 }
__global__ void residual_kernel(const float4* __restrict__ obs,
                                const float* __restrict__ points,
                                const float4* __restrict__ cam_mat,
                                float2* __restrict__ out,
                                int N) {
    int i = blockIdx.x * blockDim.x + threadIdx.x;
    int stride = gridDim.x * blockDim.x;
    for (; i < N; i += stride) {
        float4 o = obs[i];
        int cam = (int)o.x;
        int pt = (int)o.y;

        float4 m0 = cam_mat[3 * cam + 0];
        float4 m1 = cam_mat[3 * cam + 1];
        float4 m2 = cam_mat[3 * cam + 2];

        float px = points[3 * pt + 0];
        float py = points[3 * pt + 1];
        float pz = points[3 * pt + 2];

        float projx = m0.x * px + m0.y * py + m0.z * pz + m2.y;
        float projy = m0.w * px + m1.x * py + m1.y * pz + m2.z;
        float projz = m1.z * px + m1.w * py + m2.x * pz + m2.w;

        float invz = 1.0f / projz;
        float2 r;
        r.x = projx * invz - o.z;
        r.y = projy * invz - o.w;
        out[i] = r;
    }
}

extern "C" void kernel_launch(void* const* d_in, const int* in_sizes, int n_in,
                              void* d_out, int out_size, void* d_ws, size_t ws_size,
                              hipStream_t stream) {
    const float* obs = (const float*)d_in[0];
    const float* base_poses = (const float*)d_in[1];
    const float* rel_poses = (const float*)d_in[2];
    const float* points = (const float*)d_in[3];
    const float* intr = (const float*)d_in[4];
    const int* lookup = (const int*)d_in[5];

    int N = in_sizes[0] / 4;
    int C = in_sizes[5] / 2;

    float* cam_mat = (float*)d_ws;  // C * 12 floats = 96 KB

    cam_precompute<<<(C + 255) / 256, 256, 0, stream>>>(
        base_poses, rel_poses, intr, lookup, cam_mat, C);

    int threads = 256;
    int blocks = 4096;  // grid-stride; ~3.8 obs/thread, 16 blocks/CU
    residual_kernel<<<blocks, threads, 0, stream>>>(
        (const float4*)obs, points, (const float4*)cam_mat, (float2*)d_out, N);
}